// Round 10
// baseline (69.680 us; speedup 1.0000x reference)
//
#include <hip/hip_runtime.h>

// LinearImputer: linear interp over zero runs along time axis (B=32,T=4096,D=256 f32).
// Semantics (match JAX ref):
//   prev = last valid <= t (-1 if none); nxt = first valid >= t (T if none)
//   interior = !valid && prev>=0 && nxt<T
//   denom = max(nxt-prev-2, 1); pos = t-prev-1; out = x[prev] + (x[nxt]-x[prev])*pos/denom
// Boundary-touching runs stay zero.
//
// R10: LDS summary sharing to shrink the per-wave load burst (18 -> 8/12 loads).
// A 256-thread block = 4 waves = 4 consecutive chunks of one (b,...) column range.
// Each wave posts per-column (first-valid, last-valid) (idx,val) summaries to LDS;
// interior waves get prev/next seeds from neighbors' summaries instead of reloading
// 10 halo rows. Only block-edge waves prefetch a W=4 global halo. Rare all-zero-chunk
// columns escalate to the global walk (2-row batched). Emit = R3 quadratic (proven).
// Ledger: VALU count (R5), halo depth (R7), VGPR-heavy variants (R4/R8), VGPR cap
// (R6), block size (R9) -- all neutral or worse. This attacks the one untested axis:
// VMEM burst depth per wave.

typedef float f32x4 __attribute__((ext_vector_type(4)));

constexpr int B = 32, T = 4096, D = 256;
constexpr int L = 8;        // rows per chunk (per wave)
constexpr int W = 4;        // halo rows prefetched at block edges
constexpr int NC = T / L;   // 512
constexpr int C4 = D / 4;   // 64
constexpr int CPB = 4;      // chunks (waves) per block

__global__ __launch_bounds__(256)
void LinearImputer_kernel(const float* __restrict__ x, float* __restrict__ out) {
    const int tid = threadIdx.x;
    const int l   = tid & 63;           // column group; col = 4*l + cc
    const int wid = tid >> 6;           // chunk-in-block == wave id
    const int bcBase = blockIdx.x * CPB;
    const int bc = bcBase + wid;
    const int c  = bc & (NC - 1);       // chunk index (wave-uniform)
    const int b  = bc >> 9;             // same b for all 4 chunks (512 % 4 == 0)
    const int t0 = c * L;
    const int t1 = t0 + L;
    const int cFirst  = bcBase & (NC - 1);
    const int blockT0 = cFirst * L;
    const int blockT1 = blockT0 + CPB * L;

    const f32x4* __restrict__ x4 = (const f32x4*)x;
    f32x4* __restrict__       o4 = (f32x4*)out;
    const size_t base = ((size_t)b * T) * C4 + l;

    const bool haloB = (wid == 0) && (c > 0);             // wave-uniform
    const bool haloF = (wid == CPB - 1) && (c < NC - 1);  // wave-uniform

    // ---- load burst: 8 main rows (+4 halo rows for the edge waves only) ----
    f32x4 hb[W], hf[W];
    if (haloB) {
        #pragma unroll
        for (int w = 0; w < W; ++w) hb[w] = x4[base + (size_t)(t0 - 1 - w) * C4];
    }
    if (haloF) {
        #pragma unroll
        for (int w = 0; w < W; ++w) hf[w] = x4[base + (size_t)(t1 + w) * C4];
    }
    float v[L][4];
    #pragma unroll
    for (int j = 0; j < L; ++j) {
        f32x4 tv = x4[base + (size_t)(t0 + j) * C4];
        v[j][0] = tv.x; v[j][1] = tv.y; v[j][2] = tv.z; v[j][3] = tv.w;
    }

    // ---- per-column chunk summaries: first/last valid (idx,val) ----
    int topI[4]; float topV[4]; int botI[4]; float botV[4]; int anyZ = 0;
    #pragma unroll
    for (int cc = 0; cc < 4; ++cc) { topI[cc] = -1; topV[cc] = 0.0f; botI[cc] = -1; botV[cc] = 0.0f; }
    #pragma unroll
    for (int j = 0; j < L; ++j) {
        #pragma unroll
        for (int cc = 0; cc < 4; ++cc) {
            float val = v[j][cc];
            if (val != 0.0f) {
                if (topI[cc] < 0) { topI[cc] = t0 + j; topV[cc] = val; }
                botI[cc] = t0 + j; botV[cc] = val;
            } else {
                anyZ |= (1 << cc);
            }
        }
    }

    __shared__ int   sTI[CPB][D]; __shared__ float sTV[CPB][D];
    __shared__ int   sBI[CPB][D]; __shared__ float sBV[CPB][D];
    #pragma unroll
    for (int cc = 0; cc < 4; ++cc) {
        const int col = l * 4 + cc;
        sTI[wid][col] = topI[cc]; sTV[wid][col] = topV[cc];
        sBI[wid][col] = botI[cc]; sBV[wid][col] = botV[cc];
    }
    __syncthreads();

    // ---- prev seed: nearest preceding in-block chunk's bottom summary ----
    int pi[4]; float pv[4];
    #pragma unroll
    for (int cc = 0; cc < 4; ++cc) { pi[cc] = -1; pv[cc] = 0.0f; }
    #pragma unroll
    for (int k = 1; k < CPB; ++k) {
        if (wid >= k) {                       // wave-uniform
            const int kw = wid - k;
            #pragma unroll
            for (int cc = 0; cc < 4; ++cc)
                if (pi[cc] < 0) {
                    int bi = sBI[kw][l * 4 + cc];
                    if (bi >= 0) { pi[cc] = bi; pv[cc] = sBV[kw][l * 4 + cc]; }
                }
        }
    }
    if (haloB) {
        #pragma unroll
        for (int w = 0; w < W; ++w) {
            float h[4] = {hb[w].x, hb[w].y, hb[w].z, hb[w].w};
            #pragma unroll
            for (int cc = 0; cc < 4; ++cc)
                if (pi[cc] < 0 && h[cc] != 0.0f) { pi[cc] = t0 - 1 - w; pv[cc] = h[cc]; }
        }
    }
    {   // rare global walk (column all-zero back to block edge / halo depth)
        int pending = 0;
        #pragma unroll
        for (int cc = 0; cc < 4; ++cc)
            if (((anyZ >> cc) & 1) && pi[cc] < 0) pending |= (1 << cc);
        if (pending && cFirst > 0) {
            int tt = haloB ? (t0 - 1 - W) : (blockT0 - 1);
            while (pending && tt >= 0) {
                f32x4 a0 = x4[base + (size_t)tt * C4];
                const bool has2 = (tt - 1) >= 0;
                f32x4 a1;
                if (has2) a1 = x4[base + (size_t)(tt - 1) * C4];
                float h0[4] = {a0.x, a0.y, a0.z, a0.w};
                #pragma unroll
                for (int cc = 0; cc < 4; ++cc)
                    if (((pending >> cc) & 1) && h0[cc] != 0.0f) {
                        pi[cc] = tt; pv[cc] = h0[cc]; pending &= ~(1 << cc);
                    }
                if (has2 && pending) {
                    float h1[4] = {a1.x, a1.y, a1.z, a1.w};
                    #pragma unroll
                    for (int cc = 0; cc < 4; ++cc)
                        if (((pending >> cc) & 1) && h1[cc] != 0.0f) {
                            pi[cc] = tt - 1; pv[cc] = h1[cc]; pending &= ~(1 << cc);
                        }
                }
                tt -= 2;
            }
        }
    }

    // ---- next seed: nearest following in-block chunk's top summary ----
    int ni[4]; float nv[4];
    #pragma unroll
    for (int cc = 0; cc < 4; ++cc) { ni[cc] = T; nv[cc] = 0.0f; }
    #pragma unroll
    for (int k = 1; k < CPB; ++k) {
        if (wid + k < CPB) {                  // wave-uniform
            const int kw = wid + k;
            #pragma unroll
            for (int cc = 0; cc < 4; ++cc)
                if (ni[cc] == T) {
                    int ti = sTI[kw][l * 4 + cc];
                    if (ti >= 0) { ni[cc] = ti; nv[cc] = sTV[kw][l * 4 + cc]; }
                }
        }
    }
    if (haloF) {
        #pragma unroll
        for (int w = 0; w < W; ++w) {
            float h[4] = {hf[w].x, hf[w].y, hf[w].z, hf[w].w};
            #pragma unroll
            for (int cc = 0; cc < 4; ++cc)
                if (ni[cc] == T && h[cc] != 0.0f) { ni[cc] = t1 + w; nv[cc] = h[cc]; }
        }
    }
    {   // rare global walk forward
        int pending = 0;
        #pragma unroll
        for (int cc = 0; cc < 4; ++cc)
            if (((anyZ >> cc) & 1) && ni[cc] == T) pending |= (1 << cc);
        if (pending && blockT1 < T) {
            int tt = haloF ? (t1 + W) : blockT1;
            while (pending && tt < T) {
                f32x4 a0 = x4[base + (size_t)tt * C4];
                const bool has2 = (tt + 1) < T;
                f32x4 a1;
                if (has2) a1 = x4[base + (size_t)(tt + 1) * C4];
                float h0[4] = {a0.x, a0.y, a0.z, a0.w};
                #pragma unroll
                for (int cc = 0; cc < 4; ++cc)
                    if (((pending >> cc) & 1) && h0[cc] != 0.0f) {
                        ni[cc] = tt; nv[cc] = h0[cc]; pending &= ~(1 << cc);
                    }
                if (has2 && pending) {
                    float h1[4] = {a1.x, a1.y, a1.z, a1.w};
                    #pragma unroll
                    for (int cc = 0; cc < 4; ++cc)
                        if (((pending >> cc) & 1) && h1[cc] != 0.0f) {
                            ni[cc] = tt + 1; nv[cc] = h1[cc]; pending &= ~(1 << cc);
                        }
                }
                tt += 2;
            }
        }
    }

    // ---- forward emit: prev-carry + unrolled in-chunk next-scan (R3 form) ----
    #pragma unroll
    for (int j = 0; j < L; ++j) {
        float o[4];
        #pragma unroll
        for (int cc = 0; cc < 4; ++cc) {
            float val = v[j][cc];
            if (val != 0.0f) {
                o[cc] = val; pi[cc] = t0 + j; pv[cc] = val;
            } else {
                int nxi = ni[cc]; float nxv = nv[cc];
                #pragma unroll
                for (int k = L - 1; k > j; --k)
                    if (v[k][cc] != 0.0f) { nxi = t0 + k; nxv = v[k][cc]; }
                if (pi[cc] >= 0 && nxi < T) {
                    int denom = nxi - pi[cc] - 2;        // run_len - 1
                    if (denom < 1) denom = 1;
                    float frac = __fdividef((float)(t0 + j - pi[cc] - 1), (float)denom);
                    o[cc] = pv[cc] + (nxv - pv[cc]) * frac;
                } else {
                    o[cc] = 0.0f;                        // boundary-touching run
                }
            }
        }
        f32x4 ov; ov.x = o[0]; ov.y = o[1]; ov.z = o[2]; ov.w = o[3];
        __builtin_nontemporal_store(ov, &o4[base + (size_t)(t0 + j) * C4]);
    }
}

extern "C" void kernel_launch(void* const* d_in, const int* in_sizes, int n_in,
                              void* d_out, int out_size, void* d_ws, size_t ws_size,
                              hipStream_t stream) {
    const float* x = (const float*)d_in[0];
    float* out = (float*)d_out;
    const int total_blocks = (B * NC) / CPB;   // 4096
    dim3 grid(total_blocks), block(256);
    LinearImputer_kernel<<<grid, block, 0, stream>>>(x, out);
}

// Round 11
// 56.519 us; speedup vs baseline: 1.2329x; 1.2329x over previous
//
#include <hip/hip_runtime.h>

// LinearImputer: linear interp over zero runs along time axis (B=32,T=4096,D=256 f32).
// Semantics (match JAX ref):
//   prev = last valid <= t (-1 if none); nxt = first valid >= t (T if none)
//   interior = !valid && prev>=0 && nxt<T
//   denom = max(nxt-prev-2, 1); pos = t-prev-1; out = x[prev] + (x[nxt]-x[prev])*pos/denom
// Boundary-touching runs stay zero.
//
// R11 = R7 body EXACTLY (best: 54.1us, VGPR 52), single delta: plain f32x4 stores
// instead of __builtin_nontemporal_store (tests whether NT bypassing L2
// write-combining caps write throughput; fillBuffer sustains 6.9 TB/s via cached
// stores). Ledger of refuted knobs: VALU count (R5), halo depth/fallback (R7),
// VGPR-heavy restructures (R4/R8), VGPR cap (R6), block 1024 (R9), LDS summary
// sharing (R10). If this is neutral, 54us = 82% of D2D-copy rate is the floor.

typedef float f32x4 __attribute__((ext_vector_type(4)));

constexpr int B = 32, T = 4096, D = 256;
constexpr int L = 8;        // rows per thread
constexpr int W = 5;        // halo rows prefetched per side
constexpr int NC = T / L;   // 512
constexpr int C4 = D / 4;   // 64

__global__ __launch_bounds__(256)
void LinearImputer_kernel(const float* __restrict__ x, float* __restrict__ out) {
    const int g  = blockIdx.x * 256 + threadIdx.x;
    const int l  = g & (C4 - 1);        // float4 column group
    const int bc = g >> 6;
    const int c  = bc & (NC - 1);       // chunk index (wave-uniform)
    const int b  = bc >> 9;
    const int t0 = c * L;
    const int t1 = t0 + L;

    const f32x4* __restrict__ x4 = (const f32x4*)x;
    f32x4* __restrict__       o4 = (f32x4*)out;
    const size_t base = ((size_t)b * T) * C4 + l;

    const bool hasB = (c > 0);          // wave-uniform
    const bool hasF = (c < NC - 1);

    // ---- issue ALL loads up-front: 8 main + 5 back-halo + 5 fwd-halo ----
    f32x4 hb4[W], hf4[W];
    if (hasB) {
        #pragma unroll
        for (int w = 0; w < W; ++w) hb4[w] = x4[base + (size_t)(t0 - 1 - w) * C4];
    }
    if (hasF) {
        #pragma unroll
        for (int w = 0; w < W; ++w) hf4[w] = x4[base + (size_t)(t1 + w) * C4];
    }
    float v[L][4];
    #pragma unroll
    for (int j = 0; j < L; ++j) {
        f32x4 tv = x4[base + (size_t)(t0 + j) * C4];
        v[j][0] = tv.x; v[j][1] = tv.y; v[j][2] = tv.z; v[j][3] = tv.w;
    }

    // ---- backward halo -> prev carry (pi,pv) ----
    int pi[4]; float pv[4];
    #pragma unroll
    for (int cc = 0; cc < 4; ++cc) { pi[cc] = -1; pv[cc] = 0.0f; }
    if (hasB) {
        #pragma unroll
        for (int w = 0; w < W; ++w) {
            float h[4] = {hb4[w].x, hb4[w].y, hb4[w].z, hb4[w].w};
            #pragma unroll
            for (int cc = 0; cc < 4; ++cc)
                if (pi[cc] < 0 && h[cc] != 0.0f) { pi[cc] = t0 - 1 - w; pv[cc] = h[cc]; }
        }
        // rare deep-run fallback (per-column prob 0.3^6 ~ 0.07%), 2 rows/iter
        int pending = 0;
        #pragma unroll
        for (int cc = 0; cc < 4; ++cc)
            if (v[0][cc] == 0.0f && pi[cc] < 0) pending |= (1 << cc);
        if (pending) {
            int tt = t0 - 1 - W;
            while (pending && tt >= 0) {
                f32x4 a0 = x4[base + (size_t)tt * C4];
                const bool has2 = (tt - 1) >= 0;
                f32x4 a1;
                if (has2) a1 = x4[base + (size_t)(tt - 1) * C4];
                float h0[4] = {a0.x, a0.y, a0.z, a0.w};
                #pragma unroll
                for (int cc = 0; cc < 4; ++cc)
                    if (((pending >> cc) & 1) && h0[cc] != 0.0f) {
                        pi[cc] = tt; pv[cc] = h0[cc]; pending &= ~(1 << cc);
                    }
                if (has2 && pending) {
                    float h1[4] = {a1.x, a1.y, a1.z, a1.w};
                    #pragma unroll
                    for (int cc = 0; cc < 4; ++cc)
                        if (((pending >> cc) & 1) && h1[cc] != 0.0f) {
                            pi[cc] = tt - 1; pv[cc] = h1[cc]; pending &= ~(1 << cc);
                        }
                }
                tt -= 2;
            }
        }
    }

    // ---- forward halo -> next seed (ni,nv) ----
    int ni[4]; float nv[4];
    #pragma unroll
    for (int cc = 0; cc < 4; ++cc) { ni[cc] = T; nv[cc] = 0.0f; }
    if (hasF) {
        #pragma unroll
        for (int w = 0; w < W; ++w) {
            float h[4] = {hf4[w].x, hf4[w].y, hf4[w].z, hf4[w].w};
            #pragma unroll
            for (int cc = 0; cc < 4; ++cc)
                if (ni[cc] == T && h[cc] != 0.0f) { ni[cc] = t1 + w; nv[cc] = h[cc]; }
        }
        int pending = 0;
        #pragma unroll
        for (int cc = 0; cc < 4; ++cc)
            if (v[L - 1][cc] == 0.0f && ni[cc] == T) pending |= (1 << cc);
        if (pending) {
            int tt = t1 + W;
            while (pending && tt < T) {
                f32x4 a0 = x4[base + (size_t)tt * C4];
                const bool has2 = (tt + 1) < T;
                f32x4 a1;
                if (has2) a1 = x4[base + (size_t)(tt + 1) * C4];
                float h0[4] = {a0.x, a0.y, a0.z, a0.w};
                #pragma unroll
                for (int cc = 0; cc < 4; ++cc)
                    if (((pending >> cc) & 1) && h0[cc] != 0.0f) {
                        ni[cc] = tt; nv[cc] = h0[cc]; pending &= ~(1 << cc);
                    }
                if (has2 && pending) {
                    float h1[4] = {a1.x, a1.y, a1.z, a1.w};
                    #pragma unroll
                    for (int cc = 0; cc < 4; ++cc)
                        if (((pending >> cc) & 1) && h1[cc] != 0.0f) {
                            ni[cc] = tt + 1; nv[cc] = h1[cc]; pending &= ~(1 << cc);
                        }
                }
                tt += 2;
            }
        }
    }

    // ---- forward emit: prev-carry + unrolled in-chunk next-scan (R3 form) ----
    #pragma unroll
    for (int j = 0; j < L; ++j) {
        float o[4];
        #pragma unroll
        for (int cc = 0; cc < 4; ++cc) {
            float val = v[j][cc];
            if (val != 0.0f) {
                o[cc] = val; pi[cc] = t0 + j; pv[cc] = val;
            } else {
                // nearest in-chunk next wins (reverse unroll), else halo next
                int nxi = ni[cc]; float nxv = nv[cc];
                #pragma unroll
                for (int k = L - 1; k > j; --k)
                    if (v[k][cc] != 0.0f) { nxi = t0 + k; nxv = v[k][cc]; }
                if (pi[cc] >= 0 && nxi < T) {
                    int denom = nxi - pi[cc] - 2;        // run_len - 1
                    if (denom < 1) denom = 1;
                    float frac = __fdividef((float)(t0 + j - pi[cc] - 1), (float)denom);
                    o[cc] = pv[cc] + (nxv - pv[cc]) * frac;
                } else {
                    o[cc] = 0.0f;                        // boundary-touching run
                }
            }
        }
        f32x4 ov; ov.x = o[0]; ov.y = o[1]; ov.z = o[2]; ov.w = o[3];
        o4[base + (size_t)(t0 + j) * C4] = ov;           // plain store (A/B vs NT)
    }
}

extern "C" void kernel_launch(void* const* d_in, const int* in_sizes, int n_in,
                              void* d_out, int out_size, void* d_ws, size_t ws_size,
                              hipStream_t stream) {
    const float* x = (const float*)d_in[0];
    float* out = (float*)d_out;
    const int total_threads = B * NC * C4;   // 1,048,576
    dim3 grid(total_threads / 256), block(256);
    LinearImputer_kernel<<<grid, block, 0, stream>>>(x, out);
}

// Round 12
// 54.176 us; speedup vs baseline: 1.2862x; 1.0432x over previous
//
#include <hip/hip_runtime.h>

// LinearImputer: linear interp over zero runs along time axis (B=32,T=4096,D=256 f32).
// Semantics (match JAX ref):
//   prev = last valid <= t (-1 if none); nxt = first valid >= t (T if none)
//   interior = !valid && prev>=0 && nxt<T
//   denom = max(nxt-prev-2, 1); pos = t-prev-1; out = x[prev] + (x[nxt]-x[prev])*pos/denom
// Boundary-touching runs stay zero.
//
// FINAL = R7 (best measured: 54.1us = 5.2 TB/s logical, 82% of D2D-copy ceiling).
// Structure: per-thread 8 rows x 4 cols (f32x4 lane); W=5 halo prefetched in the
// same burst as main loads (no dependent-load serialization); rare deep-run global
// walk (2-row batched, P~0.07%/column); prev-carry + quadratic in-chunk next-scan
// emit; NT stores (R11 A/B: plain stores +2.4us).
// Exhausted-knob ledger: VALU count (R5), halo depth (R7), VGPR-heavy restructures
// (R4/R8), VGPR cap (R6: 246us!), block 1024 (R9), LDS sharing (R10), store type
// (R11). All neutral or worse -- this structure is at its memory/VALU joint floor.

typedef float f32x4 __attribute__((ext_vector_type(4)));

constexpr int B = 32, T = 4096, D = 256;
constexpr int L = 8;        // rows per thread
constexpr int W = 5;        // halo rows prefetched per side
constexpr int NC = T / L;   // 512
constexpr int C4 = D / 4;   // 64

__global__ __launch_bounds__(256)
void LinearImputer_kernel(const float* __restrict__ x, float* __restrict__ out) {
    const int g  = blockIdx.x * 256 + threadIdx.x;
    const int l  = g & (C4 - 1);        // float4 column group
    const int bc = g >> 6;
    const int c  = bc & (NC - 1);       // chunk index (wave-uniform)
    const int b  = bc >> 9;
    const int t0 = c * L;
    const int t1 = t0 + L;

    const f32x4* __restrict__ x4 = (const f32x4*)x;
    f32x4* __restrict__       o4 = (f32x4*)out;
    const size_t base = ((size_t)b * T) * C4 + l;

    const bool hasB = (c > 0);          // wave-uniform
    const bool hasF = (c < NC - 1);

    // ---- issue ALL loads up-front: 8 main + 5 back-halo + 5 fwd-halo ----
    f32x4 hb4[W], hf4[W];
    if (hasB) {
        #pragma unroll
        for (int w = 0; w < W; ++w) hb4[w] = x4[base + (size_t)(t0 - 1 - w) * C4];
    }
    if (hasF) {
        #pragma unroll
        for (int w = 0; w < W; ++w) hf4[w] = x4[base + (size_t)(t1 + w) * C4];
    }
    float v[L][4];
    #pragma unroll
    for (int j = 0; j < L; ++j) {
        f32x4 tv = x4[base + (size_t)(t0 + j) * C4];
        v[j][0] = tv.x; v[j][1] = tv.y; v[j][2] = tv.z; v[j][3] = tv.w;
    }

    // ---- backward halo -> prev carry (pi,pv) ----
    int pi[4]; float pv[4];
    #pragma unroll
    for (int cc = 0; cc < 4; ++cc) { pi[cc] = -1; pv[cc] = 0.0f; }
    if (hasB) {
        #pragma unroll
        for (int w = 0; w < W; ++w) {
            float h[4] = {hb4[w].x, hb4[w].y, hb4[w].z, hb4[w].w};
            #pragma unroll
            for (int cc = 0; cc < 4; ++cc)
                if (pi[cc] < 0 && h[cc] != 0.0f) { pi[cc] = t0 - 1 - w; pv[cc] = h[cc]; }
        }
        // rare deep-run fallback (per-column prob 0.3^6 ~ 0.07%), 2 rows/iter
        int pending = 0;
        #pragma unroll
        for (int cc = 0; cc < 4; ++cc)
            if (v[0][cc] == 0.0f && pi[cc] < 0) pending |= (1 << cc);
        if (pending) {
            int tt = t0 - 1 - W;
            while (pending && tt >= 0) {
                f32x4 a0 = x4[base + (size_t)tt * C4];
                const bool has2 = (tt - 1) >= 0;
                f32x4 a1;
                if (has2) a1 = x4[base + (size_t)(tt - 1) * C4];
                float h0[4] = {a0.x, a0.y, a0.z, a0.w};
                #pragma unroll
                for (int cc = 0; cc < 4; ++cc)
                    if (((pending >> cc) & 1) && h0[cc] != 0.0f) {
                        pi[cc] = tt; pv[cc] = h0[cc]; pending &= ~(1 << cc);
                    }
                if (has2 && pending) {
                    float h1[4] = {a1.x, a1.y, a1.z, a1.w};
                    #pragma unroll
                    for (int cc = 0; cc < 4; ++cc)
                        if (((pending >> cc) & 1) && h1[cc] != 0.0f) {
                            pi[cc] = tt - 1; pv[cc] = h1[cc]; pending &= ~(1 << cc);
                        }
                }
                tt -= 2;
            }
        }
    }

    // ---- forward halo -> next seed (ni,nv) ----
    int ni[4]; float nv[4];
    #pragma unroll
    for (int cc = 0; cc < 4; ++cc) { ni[cc] = T; nv[cc] = 0.0f; }
    if (hasF) {
        #pragma unroll
        for (int w = 0; w < W; ++w) {
            float h[4] = {hf4[w].x, hf4[w].y, hf4[w].z, hf4[w].w};
            #pragma unroll
            for (int cc = 0; cc < 4; ++cc)
                if (ni[cc] == T && h[cc] != 0.0f) { ni[cc] = t1 + w; nv[cc] = h[cc]; }
        }
        int pending = 0;
        #pragma unroll
        for (int cc = 0; cc < 4; ++cc)
            if (v[L - 1][cc] == 0.0f && ni[cc] == T) pending |= (1 << cc);
        if (pending) {
            int tt = t1 + W;
            while (pending && tt < T) {
                f32x4 a0 = x4[base + (size_t)tt * C4];
                const bool has2 = (tt + 1) < T;
                f32x4 a1;
                if (has2) a1 = x4[base + (size_t)(tt + 1) * C4];
                float h0[4] = {a0.x, a0.y, a0.z, a0.w};
                #pragma unroll
                for (int cc = 0; cc < 4; ++cc)
                    if (((pending >> cc) & 1) && h0[cc] != 0.0f) {
                        ni[cc] = tt; nv[cc] = h0[cc]; pending &= ~(1 << cc);
                    }
                if (has2 && pending) {
                    float h1[4] = {a1.x, a1.y, a1.z, a1.w};
                    #pragma unroll
                    for (int cc = 0; cc < 4; ++cc)
                        if (((pending >> cc) & 1) && h1[cc] != 0.0f) {
                            ni[cc] = tt + 1; nv[cc] = h1[cc]; pending &= ~(1 << cc);
                        }
                }
                tt += 2;
            }
        }
    }

    // ---- forward emit: prev-carry + unrolled in-chunk next-scan (R3 form) ----
    #pragma unroll
    for (int j = 0; j < L; ++j) {
        float o[4];
        #pragma unroll
        for (int cc = 0; cc < 4; ++cc) {
            float val = v[j][cc];
            if (val != 0.0f) {
                o[cc] = val; pi[cc] = t0 + j; pv[cc] = val;
            } else {
                // nearest in-chunk next wins (reverse unroll), else halo next
                int nxi = ni[cc]; float nxv = nv[cc];
                #pragma unroll
                for (int k = L - 1; k > j; --k)
                    if (v[k][cc] != 0.0f) { nxi = t0 + k; nxv = v[k][cc]; }
                if (pi[cc] >= 0 && nxi < T) {
                    int denom = nxi - pi[cc] - 2;        // run_len - 1
                    if (denom < 1) denom = 1;
                    float frac = __fdividef((float)(t0 + j - pi[cc] - 1), (float)denom);
                    o[cc] = pv[cc] + (nxv - pv[cc]) * frac;
                } else {
                    o[cc] = 0.0f;                        // boundary-touching run
                }
            }
        }
        f32x4 ov; ov.x = o[0]; ov.y = o[1]; ov.z = o[2]; ov.w = o[3];
        __builtin_nontemporal_store(ov, &o4[base + (size_t)(t0 + j) * C4]);
    }
}

extern "C" void kernel_launch(void* const* d_in, const int* in_sizes, int n_in,
                              void* d_out, int out_size, void* d_ws, size_t ws_size,
                              hipStream_t stream) {
    const float* x = (const float*)d_in[0];
    float* out = (float*)d_out;
    const int total_threads = B * NC * C4;   // 1,048,576
    dim3 grid(total_threads / 256), block(256);
    LinearImputer_kernel<<<grid, block, 0, stream>>>(x, out);
}